// Round 15
// baseline (574.471 us; speedup 1.0000x reference)
//
#include <hip/hip_runtime.h>
#include <hip/hip_bf16.h>

#define H 24
#define HD 128
#define DMODEL 3072
#define S_IMG 2048
#define S_TXT 512
#define S_ALL 2560
#define EMB 4096
#define N_IP 64
#define SM_SCALE 0.08838834764831845f  // 1/sqrt(128)

typedef __attribute__((ext_vector_type(8))) short short8;
typedef __attribute__((ext_vector_type(4))) float f32x4;
typedef __attribute__((ext_vector_type(16))) float f32x16;

__device__ inline unsigned short f2bf(float f) {
    unsigned u = __builtin_bit_cast(unsigned, f);
    return (unsigned short)((u + 0x7fffu + ((u >> 16) & 1u)) >> 16);
}
__device__ inline unsigned pk2(float a, float b) {
    return (unsigned)f2bf(a) | ((unsigned)f2bf(b) << 16);
}
__device__ inline float bf2f(unsigned short u) {
    unsigned x = ((unsigned)u) << 16;
    return __builtin_bit_cast(float, x);
}

__device__ inline void gload16(const void* g, void* l) {
    __builtin_amdgcn_global_load_lds(
        (const __attribute__((address_space(1))) unsigned int*)g,
        (__attribute__((address_space(3))) unsigned int*)(unsigned int)(unsigned long long)l,
        16, 0, 0);
}

// ---------------- merged f32 -> bf16 casts (11 segments; Wo/Wao deferred into gemm8) ----------------
struct CastSegs {
    const float* src[13];
    unsigned short* dst[13];
    int n8[13];
    int ntot8[13];
    int bstart[14];
};

__global__ __launch_bounds__(256)
void castall(CastSegs cs)
{
    int b = blockIdx.x, seg = 0;
    while (seg < 12 && b >= cs.bstart[seg + 1]) seg++;
    int nb = cs.bstart[seg + 1] - cs.bstart[seg];
    int lb = b - cs.bstart[seg];
    const float* in = cs.src[seg];
    unsigned short* out = cs.dst[seg];
    int n8 = cs.n8[seg], ntot = cs.ntot8[seg];
    for (int i = lb * 256 + threadIdx.x; i < ntot; i += nb * 256) {
        int4 o;
        if (i < n8) {
            const float4* p = (const float4*)(in + (size_t)i * 8);
            float4 a = p[0], bb = p[1];
            o.x = pk2(a.x, a.y); o.y = pk2(a.z, a.w);
            o.z = pk2(bb.x, bb.y); o.w = pk2(bb.z, bb.w);
        } else {
            o.x = 0; o.y = 0; o.z = 0; o.w = 0;
        }
        *(int4*)(out + (size_t)i * 8) = o;
    }
}

__global__ __launch_bounds__(256)
void bcat2(const float* __restrict__ q0, const float* __restrict__ k0, const float* __restrict__ v0,
           const float* __restrict__ q1, const float* __restrict__ k1, const float* __restrict__ v1,
           float* __restrict__ d0, float* __restrict__ d1)
{
    int i = blockIdx.x * 256 + threadIdx.x;  // 18432
    int which = i >= 3 * DMODEL;
    int j = which ? i - 3 * DMODEL : i;
    const float* a = which ? q1 : q0;
    const float* b = which ? k1 : k0;
    const float* c = which ? v1 : v0;
    float v = (j < DMODEL) ? a[j] : ((j < 2 * DMODEL) ? b[j - DMODEL] : c[j - 2 * DMODEL]);
    (which ? d1 : d0)[j] = v;
}

// ---------------- GEMM pipelined: 256x128 tile, BK=32, DOUBLE buffer (48KB -> 3 blocks/CU) ----------
// Range-routed up to 3 sets + optional cast-role tail blocks; long-pole blocks (ip K=4096)
// routed first so they run concurrent with the QKV round.
// Depth-1 prefetch: STAGE(t+1) issued before compute(t); vmcnt(0)+barrier at tile end is
// covered by the ~1700-cyc tile window (>= 900-cyc HBM latency) + 24-wave/CU TLP.
// 8 waves as 4M x 2N; acc[4][4] = 64 AGPR; 56 VGPR -> 120 regs/wave. launch_bounds (512,4):
// do NOT raise the min-waves arg — (512,6) caps regs at 85 and spills acc (r11 disaster).
// LDS slot swizzle = g ^ ((row>>1)&3): 2-way bank aliasing (free), both sides (rule #21).
struct GSet {
    const unsigned short* A;
    const unsigned short* B;
    const float* bias;
    void* C;
    int N, K, nbn;
};

template<int OUTBF>
__global__ __launch_bounds__(512, 4)
void gemm8(GSet s0, GSet s1, GSet s2, int e0, int e1, int e2,
           const float* cs0, unsigned short* cd0,
           const float* cs1, unsigned short* cd1, int cn8)
{
    __shared__ char sm[49152];   // 2 bufs x (A 16K [256x64B] + B 8K [128x64B])
    const int tid = threadIdx.x, lane = tid & 63, wid = tid >> 6;
    const int wm = wid >> 1, wn = wid & 1;       // 4M x 2N wave grid
    const int r15 = lane & 15, g = lane >> 4;

    int nwg = gridDim.x;
    int t0 = (blockIdx.x & 7) * (nwg >> 3) + (blockIdx.x >> 3);

    if (t0 >= e2) {              // cast-role tail blocks (Wo/Wao f32->bf16), 64 blocks each
        int lb = t0 - e2;        // 0..127
        const float* src = (lb >> 6) ? cs1 : cs0;
        unsigned short* dst = (lb >> 6) ? cd1 : cd0;
        int b = lb & 63;
        for (int i = b * 512 + tid; i < cn8; i += 64 * 512) {
            const float4* p = (const float4*)(src + (size_t)i * 8);
            float4 a = p[0], bb = p[1];
            int4 o;
            o.x = pk2(a.x, a.y); o.y = pk2(a.z, a.w);
            o.z = pk2(bb.x, bb.y); o.w = pk2(bb.z, bb.w);
            *(int4*)(dst + (size_t)i * 8) = o;
        }
        return;
    }

    GSet S; int local;
    if (t0 < e0)      { S = s0; local = t0; }
    else if (t0 < e1) { S = s1; local = t0 - e0; }
    else              { S = s2; local = t0 - e1; }
    const int mb = local / S.nbn, nb = local - mb * S.nbn;
    const int m0 = mb * 256, n0 = nb * 128;
    const int K = S.K, N = S.N;
    const unsigned short* A = S.A;
    const unsigned short* B = S.B;
    const float* bias = S.bias;

    // staging: linear LDS dest, inverse-swizzled global source (rule #21); f(row) = (row>>1)&3
    const int fA0 = tid, fA1 = 512 + tid;
    const int rA0 = fA0 >> 2, sA0 = fA0 & 3;
    const int rA1 = fA1 >> 2, sA1 = fA1 & 3;
    const int rB = tid >> 2, sB = tid & 3;
    const unsigned short* Asrc0 = A + (size_t)(m0 + rA0) * K + ((sA0 ^ ((rA0 >> 1) & 3)) << 3);
    const unsigned short* Asrc1 = A + (size_t)(m0 + rA1) * K + ((sA1 ^ ((rA1 >> 1) & 3)) << 3);
    const unsigned short* Bsrc  = B + (size_t)(n0 + rB) * K + ((sB ^ ((rB >> 1) & 3)) << 3);

    f32x4 acc[4][4];
    #pragma unroll
    for (int i = 0; i < 4; i++)
        #pragma unroll
        for (int j = 0; j < 4; j++)
            acc[i][j] = {0.f, 0.f, 0.f, 0.f};

    const int nt = K >> 5;

    auto STAGE = [&](char* d, int kt) {
        gload16(Asrc0 + (kt << 5), d + fA0 * 16);
        gload16(Asrc1 + (kt << 5), d + fA1 * 16);
        gload16(Bsrc  + (kt << 5), d + 16384 + tid * 16);
    };

    STAGE(sm, 0);
    asm volatile("s_waitcnt vmcnt(0)" ::: "memory");
    __builtin_amdgcn_s_barrier();

    for (int t = 0; t < nt; t++) {
        char* cur = sm + (t & 1) * 24576;
        char* oth = sm + ((t + 1) & 1) * 24576;
        if (t + 1 < nt) STAGE(oth, t + 1);   // prefetch hides under compute + 24-wave TLP
        const char* As = cur;
        const char* Bs = cur + 16384;
        short8 bfr[4];
        #pragma unroll
        for (int ni = 0; ni < 4; ni++) {
            int brow = wn * 64 + ni * 16 + r15;
            bfr[ni] = *(const short8*)(Bs + brow * 64 + ((g ^ ((brow >> 1) & 3)) << 4));
        }
        __builtin_amdgcn_s_setprio(1);
        #pragma unroll
        for (int mi = 0; mi < 4; mi++) {
            int arow = wm * 64 + mi * 16 + r15;
            short8 af = *(const short8*)(As + arow * 64 + ((g ^ ((arow >> 1) & 3)) << 4));
            #pragma unroll
            for (int ni = 0; ni < 4; ni++)
                acc[mi][ni] = __builtin_amdgcn_mfma_f32_16x16x32_bf16(af, bfr[ni], acc[mi][ni], 0, 0, 0);
        }
        __builtin_amdgcn_s_setprio(0);
        asm volatile("s_waitcnt vmcnt(0)" ::: "memory");   // drain covered by compute window
        __builtin_amdgcn_s_barrier();
    }

    #pragma unroll
    for (int mi = 0; mi < 4; mi++) {
        #pragma unroll
        for (int ni = 0; ni < 4; ni++) {
            int col = n0 + wn * 64 + ni * 16 + r15;
            float bv = bias ? bias[col] : 0.f;
            #pragma unroll
            for (int r = 0; r < 4; r++) {
                int grow = m0 + wm * 64 + mi * 16 + g * 4 + r;
                float v = acc[mi][ni][r] + bv;
                if (OUTBF)
                    ((unsigned short*)S.C)[(size_t)grow * N + col] = f2bf(v);
                else
                    ((float*)S.C)[(size_t)grow * N + col] = v;
            }
        }
    }
}

// ---------------- fused RMS norm + RoPE for Q and K (bf16 in, bf16 out) ----------------
__global__ __launch_bounds__(256)
void rmsropeQK(const unsigned short* __restrict__ qkvb,
               const float* __restrict__ nqw, const float* __restrict__ nkw,
               const float* __restrict__ naqw, const float* __restrict__ nakw,
               const float* __restrict__ cosb, const float* __restrict__ sinb,
               unsigned short* __restrict__ qb, unsigned short* __restrict__ kb,
               unsigned short* __restrict__ ipq)
{
    int wg = blockIdx.x * 4 + (threadIdx.x >> 6);
    int lane = threadIdx.x & 63;
    int s = wg / H, h = wg - s * H;
    const unsigned short* row = qkvb + (size_t)s * (3 * DMODEL);
    unsigned uq = *(const unsigned*)(row + h * HD + lane * 2);
    unsigned uk = *(const unsigned*)(row + DMODEL + h * HD + lane * 2);
    float q0 = bf2f((unsigned short)uq), q1 = bf2f((unsigned short)(uq >> 16));
    float k0 = bf2f((unsigned short)uk), k1 = bf2f((unsigned short)(uk >> 16));
    float sq = q0 * q0 + q1 * q1, sk = k0 * k0 + k1 * k1;
    #pragma unroll
    for (int off = 1; off < 64; off <<= 1) {
        sq += __shfl_xor(sq, off);
        sk += __shfl_xor(sk, off);
    }
    float rq = rsqrtf(sq * (1.f / HD) + 1e-6f) * SM_SCALE;
    float rk = rsqrtf(sk * (1.f / HD) + 1e-6f);
    const float* wq = (s < S_TXT) ? naqw : nqw;
    const float* wk = (s < S_TXT) ? nakw : nkw;
    float xq0 = q0 * rq * wq[lane * 2], xq1 = q1 * rq * wq[lane * 2 + 1];
    float xk0 = k0 * rk * wk[lane * 2], xk1 = k1 * rk * wk[lane * 2 + 1];
    if (s >= S_TXT)
        *(unsigned*)(ipq + (size_t)h * S_IMG * HD + (size_t)(s - S_TXT) * HD + lane * 2) = pk2(xq0, xq1);
    float c0 = cosb[s * HD + lane * 2], c1 = cosb[s * HD + lane * 2 + 1];
    float s0 = sinb[s * HD + lane * 2], s1 = sinb[s * HD + lane * 2 + 1];
    *(unsigned*)(qb + (size_t)h * S_ALL * HD + (size_t)s * HD + lane * 2) =
        pk2(xq0 * c0 - xq1 * s0, xq1 * c1 + xq0 * s1);
    *(unsigned*)(kb + (size_t)h * S_ALL * HD + (size_t)s * HD + lane * 2) =
        pk2(xk0 * c0 - xk1 * s0, xk1 * c1 + xk0 * s1);
}

// ---------------- V transpose: bf16 [S][stride] (col block h*HD) -> [H][HD][Stot] ----------------
__global__ __launch_bounds__(256)
void vtrans(const unsigned short* __restrict__ src, int stride,
            unsigned short* __restrict__ vt, int Stot)
{
    __shared__ unsigned short lv[64 * 130];
    int h = blockIdx.y;
    int s0 = blockIdx.x * 64;
    const unsigned short* base = src + (size_t)s0 * stride + h * HD;
    int tid = threadIdx.x;
    #pragma unroll
    for (int i = 0; i < 4; i++) {
        int slot = tid + 256 * i;
        int row = slot >> 4, c = slot & 15;
        int4 v = *(const int4*)(base + (size_t)row * stride + c * 8);
        unsigned* p = (unsigned*)(lv + row * 130 + c * 8);
        p[0] = (unsigned)v.x; p[1] = (unsigned)v.y; p[2] = (unsigned)v.z; p[3] = (unsigned)v.w;
    }
    __syncthreads();
    #pragma unroll
    for (int i = 0; i < 4; i++) {
        int slot = tid + 256 * i;
        int d = slot >> 3, c8 = slot & 7;
        unsigned w0 = lv[(c8 * 8 + 0) * 130 + d] | ((unsigned)lv[(c8 * 8 + 1) * 130 + d] << 16);
        unsigned w1 = lv[(c8 * 8 + 2) * 130 + d] | ((unsigned)lv[(c8 * 8 + 3) * 130 + d] << 16);
        unsigned w2 = lv[(c8 * 8 + 4) * 130 + d] | ((unsigned)lv[(c8 * 8 + 5) * 130 + d] << 16);
        unsigned w3 = lv[(c8 * 8 + 6) * 130 + d] | ((unsigned)lv[(c8 * 8 + 7) * 130 + d] << 16);
        int4 o = {(int)w0, (int)w1, (int)w2, (int)w3};
        *(int4*)(vt + (size_t)(h * HD + d) * Stot + s0 + c8 * 8) = o;
    }
}

// ---------------- relayout ip K: [N_IP][2*DMODEL] bf16 -> [H][N_IP][HD] bf16 ----------------
__global__ __launch_bounds__(256)
void cast_heads8(const unsigned short* __restrict__ in, unsigned short* __restrict__ out)
{
    int idx = blockIdx.x * 256 + threadIdx.x;   // 24576 = N_IP * DMODEL / 8
    int s = idx / 384;
    int rem = idx - s * 384;
    int h = rem >> 4, d8 = rem & 15;
    int4 v = *(const int4*)(in + (size_t)s * (2 * DMODEL) + h * HD + d8 * 8);
    *(int4*)(out + ((size_t)h * N_IP + s) * HD + d8 * 8) = v;
}

// ---------------- Flash attention v4: 8 warps x 32 q-rows (QBLK=256), KVBLK templated ----------
// 1D grid, XCD-chunked: each XCD owns a contiguous run of heads so the NQB q-blocks
// sharing a head's K/V are L2-co-resident (T1). grid % 8 == 0 guaranteed.
template<int MODE, int KVBLK, int NQB>  // MODE 0 = IP (write bf16 ip_hs), 1 = main (add bf16 ip)
__global__ __launch_bounds__(512, 2)
void flash4(const unsigned short* __restrict__ Q, const unsigned short* __restrict__ Kb,
            const unsigned short* __restrict__ Vt, const unsigned short* __restrict__ ipb,
            unsigned short* __restrict__ Out, int Sq, int Skv)
{
    __shared__ char sm[66560];  // K @0 (<=32K), Vt @32768 (<=32K), scl 1K @65536
    int bid = blockIdx.x;
    int gidx = (bid & 7) * (gridDim.x >> 3) + (bid >> 3);
    const int h = gidx / NQB;
    const int q0 = (gidx - h * NQB) * 256;
    const int tid = threadIdx.x, w = tid >> 6, lane = tid & 63;
    const int l31 = lane & 31, hi = lane >> 5;
    const int T2 = KVBLK / 32, K4 = KVBLK / 16, SLOTV = KVBLK / 8, NL = KVBLK / 32;
    const int VROWB = KVBLK * 2;

    const unsigned short* Qh = Q + ((size_t)h * Sq + q0 + w * 32 + l31) * HD + hi * 8;
    short8 qf[8];
    #pragma unroll
    for (int c = 0; c < 8; c++)
        qf[c] = *(const short8*)(Qh + c * 16);

    float m = -3.0e38f, lsum = 0.f;
    f32x16 o[4];
    #pragma unroll
    for (int dn = 0; dn < 4; dn++)
        #pragma unroll
        for (int r = 0; r < 16; r++) o[dn][r] = 0.f;

    const unsigned short* Kh = Kb + (size_t)h * Skv * HD;
    const unsigned short* Vth = Vt + (size_t)h * HD * Skv;
    float* scl = (float*)(sm + 65536) + w * 32;
    const int nt = Skv / KVBLK;

    for (int t = 0; t < nt; t++) {
        int kv0 = t * KVBLK;
        #pragma unroll
        for (int cc = 0; cc < NL; cc++) {
            int f = cc * 512 + tid;
            int row = f >> 4, slot = f & 15;
            gload16(Kh + (size_t)(kv0 + row) * HD + (((slot * 16) ^ ((row & 7) << 4)) >> 1),
                    sm + f * 16);
        }
        #pragma unroll
        for (int cc = 0; cc < NL; cc++) {
            int f = cc * 512 + tid;
            int d = f / SLOTV, slot = f % SLOTV;
            gload16(Vth + (size_t)d * Skv + kv0 + (((slot * 16) ^ ((d & 7) << 4)) >> 1),
                    sm + 32768 + f * 16);
        }
        __syncthreads();

        f32x16 st[T2];
        __builtin_amdgcn_s_setprio(1);
        #pragma unroll
        for (int t2 = 0; t2 < T2; t2++) {
            #pragma unroll
            for (int r = 0; r < 16; r++) st[t2][r] = 0.f;
            #pragma unroll
            for (int c = 0; c < 8; c++) {
                int krow = t2 * 32 + l31;
                short8 kf = *(const short8*)(sm + krow * 256 + ((c * 32 + hi * 16) ^ ((krow & 7) << 4)));
                st[t2] = __builtin_amdgcn_mfma_f32_32x32x16_bf16(kf, qf[c], st[t2], 0, 0, 0);
            }
        }
        __builtin_amdgcn_s_setprio(0);

        float pmax = st[0][0];
        #pragma unroll
        for (int t2 = 0; t2 < T2; t2++)
            #pragma unroll
            for (int r = 0; r < 16; r++) pmax = fmaxf(pmax, st[t2][r]);
        pmax = fmaxf(pmax, __shfl_xor(pmax, 32));

        if (!__all(pmax - m <= 8.0f)) {     // defer-max (T13)
            float mn = fmaxf(m, pmax);
            float sc = __expf(m - mn);
            m = mn;
            lsum *= sc;
            if (hi == 0) scl[l31] = sc;
            float scb[16];
            #pragma unroll
            for (int r = 0; r < 16; r++)
                scb[r] = scl[(r & 3) + 8 * (r >> 2) + 4 * hi];
            #pragma unroll
            for (int dn = 0; dn < 4; dn++)
                #pragma unroll
                for (int r = 0; r < 16; r++) o[dn][r] *= scb[r];
        }

        float psum = 0.f;
        #pragma unroll
        for (int t2 = 0; t2 < T2; t2++)
            #pragma unroll
            for (int r = 0; r < 16; r++) {
                float p = __expf(st[t2][r] - m);
                st[t2][r] = p;
                psum += p;
            }
        psum += __shfl_xor(psum, 32);
        lsum += psum;

        short8 pa[K4];
        #pragma unroll
        for (int k4 = 0; k4 < K4; k4++) {
            unsigned U  = pk2(st[(k4 * 8 + 0) >> 4][(k4 * 8 + 0) & 15], st[(k4 * 8 + 1) >> 4][(k4 * 8 + 1) & 15]);
            unsigned V  = pk2(st[(k4 * 8 + 2) >> 4][(k4 * 8 + 2) & 15], st[(k4 * 8 + 3) >> 4][(k4 * 8 + 3) & 15]);
            unsigned U2 = pk2(st[(k4 * 8 + 4) >> 4][(k4 * 8 + 4) & 15], st[(k4 * 8 + 5) >> 4][(k4 * 8 + 5) & 15]);
            unsigned V2 = pk2(st[(k4 * 8 + 6) >> 4][(k4 * 8 + 6) & 15], st[(k4 * 8 + 7) >> 4][(k4 * 8 + 7) & 15]);
            unsigned SU = __shfl_xor(U, 32), SU2 = __shfl_xor(U2, 32);
            unsigned SV = __shfl_xor(V, 32), SV2 = __shfl_xor(V2, 32);
            uint4 wv;
            wv.x = hi ? SU2 : U;
            wv.y = hi ? SV2 : V;
            wv.z = hi ? U2 : SU;
            wv.w = hi ? V2 : SV;
            pa[k4] = __builtin_bit_cast(short8, wv);
        }

        __builtin_amdgcn_s_setprio(1);
        #pragma unroll
        for (int dn = 0; dn < 4; dn++) {
            #pragma unroll
            for (int k4 = 0; k4 < K4; k4++) {
                int vrow = dn * 32 + l31;
                short8 vf = *(const short8*)(sm + 32768 + vrow * VROWB + ((k4 * 32 + hi * 16) ^ ((vrow & 7) << 4)));
                o[dn] = __builtin_amdgcn_mfma_f32_32x32x16_bf16(pa[k4], vf, o[dn], 0, 0, 0);
            }
        }
        __builtin_amdgcn_s_setprio(0);
        __syncthreads();
    }

    if (hi == 0) scl[l31] = 1.f / lsum;
    float linv[16];
    #pragma unroll
    for (int r = 0; r < 16; r++)
        linv[r] = scl[(r & 3) + 8 * (r >> 2) + 4 * hi];
    #pragma unroll
    for (int dn = 0; dn < 4; dn++) {
        #pragma unroll
        for (int r = 0; r < 16; r++) {
            int qrow = q0 + w * 32 + (r & 3) + 8 * (r >> 2) + 4 * hi;
            int col = h * HD + dn * 32 + l31;
            float val = o[dn][r] * linv[r];
            if (MODE == 1 && qrow >= S_TXT)
                val += bf2f(ipb[(size_t)(qrow - S_TXT) * DMODEL + col]);
            Out[(size_t)qrow * DMODEL + col] = f2bf(val);
        }
    }
}

// ---------------- launch ----------------
extern "C" void kernel_launch(void* const* d_in, const int* in_sizes, int n_in,
                              void* d_out, int out_size, void* d_ws, size_t ws_size,
                              hipStream_t stream)
{
    const float* hs   = (const float*)d_in[0];
    const float* enc  = (const float*)d_in[1];
    const float* iemb = (const float*)d_in[2];
    const float* cosb = (const float*)d_in[3];
    const float* sinb = (const float*)d_in[4];
    const float* Wq  = (const float*)d_in[5];  const float* bq  = (const float*)d_in[6];
    const float* Wk  = (const float*)d_in[7];  const float* bk  = (const float*)d_in[8];
    const float* Wv  = (const float*)d_in[9];  const float* bv  = (const float*)d_in[10];
    const float* Waq = (const float*)d_in[11]; const float* baq = (const float*)d_in[12];
    const float* Wak = (const float*)d_in[13]; const float* bak = (const float*)d_in[14];
    const float* Wav = (const float*)d_in[15]; const float* bav = (const float*)d_in[16];
    const float* Wo  = (const float*)d_in[17]; const float* bo  = (const float*)d_in[18];
    const float* Wao = (const float*)d_in[19]; const float* bao = (const float*)d_in[20];
    const float* nq  = (const float*)d_in[21]; const float* nk  = (const float*)d_in[22];
    const float* naq = (const float*)d_in[23]; const float* nak = (const float*)d_in[24];
    const float* Wkip = (const float*)d_in[25]; const float* Wvip = (const float*)d_in[26];
    (void)in_sizes; (void)n_in; (void)out_size; (void)ws_size;

    char* ws = (char*)d_ws;
    size_t off = 0;
    auto alloc = [&](size_t b) { char* p = ws + off; off += (b + 255) & ~(size_t)255; return p; };
    unsigned short* qkvb    = (unsigned short*)alloc((size_t)S_ALL * 3 * DMODEL * 2);  // txt rows 0..511, img 512..2559
    unsigned short* ipkvb   = (unsigned short*)alloc((size_t)256 * 2 * DMODEL * 2);    // rows 64..255 pad
    unsigned short* hs_bf   = (unsigned short*)alloc((size_t)S_IMG * DMODEL * 2);
    unsigned short* enc_bf  = (unsigned short*)alloc((size_t)S_TXT * DMODEL * 2);
    unsigned short* iemb_bf = (unsigned short*)alloc((size_t)256 * EMB * 2);           // rows 64..255 pad (zeros)
    unsigned short* Wqkv  = (unsigned short*)alloc((size_t)3 * DMODEL * DMODEL * 2);
    unsigned short* Waqkv = (unsigned short*)alloc((size_t)3 * DMODEL * DMODEL * 2);
    unsigned short* Wo_b  = (unsigned short*)alloc((size_t)DMODEL * DMODEL * 2);
    unsigned short* Wao_b = (unsigned short*)alloc((size_t)DMODEL * DMODEL * 2);
    unsigned short* Wip   = (unsigned short*)alloc((size_t)2 * DMODEL * EMB * 2);
    float* bqkv  = (float*)alloc(3 * DMODEL * 4);
    float* baqkv = (float*)alloc(3 * DMODEL * 4);
    unsigned short* qb    = (unsigned short*)alloc((size_t)H * S_ALL * HD * 2);
    unsigned short* kbf   = (unsigned short*)alloc((size_t)H * S_ALL * HD * 2);
    unsigned short* vtb   = (unsigned short*)alloc((size_t)H * HD * S_ALL * 2);
    unsigned short* ipqb  = (unsigned short*)alloc((size_t)H * S_IMG * HD * 2);
    unsigned short* ipkb  = (unsigned short*)alloc((size_t)H * N_IP * HD * 2);
    unsigned short* ipvtb = (unsigned short*)alloc((size_t)H * HD * N_IP * 2);
    unsigned short* ipbuf = (unsigned short*)alloc((size_t)S_IMG * DMODEL * 2);
    unsigned short* attnb = (unsigned short*)alloc((size_t)S_ALL * DMODEL * 2);

    const size_t DD = (size_t)DMODEL * DMODEL;
    const size_t DE = (size_t)DMODEL * EMB;
    const int D8 = (int)(DD / 8), E8 = (int)(DE / 8);

    // merged cast dispatch: activations + QKV weights + ip weights (Wo/Wao deferred into gemm8)
    CastSegs cs;
    const float* srcs[11] = {hs, enc, iemb, Wq, Wk, Wv, Waq, Wak, Wav, Wkip, Wvip};
    unsigned short* dsts[11] = {hs_bf, enc_bf, iemb_bf,
                                Wqkv, Wqkv + DD, Wqkv + 2 * DD,
                                Waqkv, Waqkv + DD, Waqkv + 2 * DD,
                                Wip, Wip + DE};
    int n8s[11]  = {S_IMG * DMODEL / 8, S_TXT * DMODEL / 8, N_IP * EMB / 8,
                    D8, D8, D8, D8, D8, D8, E8, E8};
    int nt8s[11] = {S_IMG * DMODEL / 8, S_TXT * DMODEL / 8, 256 * EMB / 8,
                    D8, D8, D8, D8, D8, D8, E8, E8};
    int acc = 0;
    for (int i = 0; i < 11; i++) {
        cs.src[i] = srcs[i]; cs.dst[i] = dsts[i];
        cs.n8[i] = n8s[i]; cs.ntot8[i] = nt8s[i];
        cs.bstart[i] = acc;
        int nb = (nt8s[i] + 8191) / 8192;
        acc += (nb < 1 ? 1 : nb);
    }
    for (int i = 11; i < 14; i++) cs.bstart[i] = acc;

    dim3 blk(256);
    castall<<<dim3(acc), blk, 0, stream>>>(cs);
    bcat2<<<dim3(72), blk, 0, stream>>>(bq, bk, bv, baq, bak, bav, bqkv, baqkv);

    // mega QKV dispatch, long-pole-first routing:
    //   ip [0,48) | img QKV [48,624) | txt QKV [624,768) | Wo/Wao cast [768,896)
    GSet sIp  = {iemb_bf, Wip,  nullptr, ipkvb,                           2 * DMODEL, EMB,    48};
    GSet sImg = {hs_bf,  Wqkv,  bqkv,  qkvb + (size_t)S_TXT * 3 * DMODEL, 3 * DMODEL, DMODEL, 72};
    GSet sTxt = {enc_bf, Waqkv, baqkv, qkvb,                              3 * DMODEL, DMODEL, 72};
    gemm8<1><<<dim3(896), dim3(512), 0, stream>>>(
        sIp, sImg, sTxt, 48, 624, 768,
        Wo, Wo_b, Wao, Wao_b, D8);

    rmsropeQK<<<dim3(15360), blk, 0, stream>>>(qkvb, nq, nk, naq, nak, cosb, sinb, qb, kbf, ipqb);
    vtrans<<<dim3(40, 24), blk, 0, stream>>>(qkvb + 2 * DMODEL, 3 * DMODEL, vtb, S_ALL);
    cast_heads8<<<dim3(96), blk, 0, stream>>>(ipkvb, ipkb);
    vtrans<<<dim3(1, 24), blk, 0, stream>>>(ipkvb + DMODEL, 2 * DMODEL, ipvtb, N_IP);

    dim3 fblk(512);
    flash4<0, 64, 8><<<dim3(192), fblk, 0, stream>>>(ipqb, ipkb, ipvtb, nullptr, ipbuf, S_IMG, N_IP);
    flash4<1, 128, 10><<<dim3(240), fblk, 0, stream>>>(qb, kbf, vtb, ipbuf, attnb, S_ALL, S_ALL);

    // out-proj dispatch: img [0,192) -> Wo, txt [192,240) -> Wao; no ip set, no cast tail
    GSet oImg = {attnb + (size_t)S_TXT * DMODEL, Wo_b,  bo,  d_out,                                DMODEL, DMODEL, 24};
    GSet oTxt = {attnb,                          Wao_b, bao, (float*)d_out + (size_t)S_IMG * DMODEL, DMODEL, DMODEL, 24};
    gemm8<0><<<dim3(240), dim3(512), 0, stream>>>(
        oImg, oTxt, oTxt, 192, 240, 240,
        nullptr, nullptr, nullptr, nullptr, 0);
}

// Round 16
// 559.391 us; speedup vs baseline: 1.0270x; 1.0270x over previous
//
#include <hip/hip_runtime.h>
#include <hip/hip_bf16.h>

#define H 24
#define HD 128
#define DMODEL 3072
#define S_IMG 2048
#define S_TXT 512
#define S_ALL 2560
#define EMB 4096
#define N_IP 64
#define SM_SCALE 0.08838834764831845f  // 1/sqrt(128)

typedef __attribute__((ext_vector_type(8))) short short8;
typedef __attribute__((ext_vector_type(4))) float f32x4;
typedef __attribute__((ext_vector_type(16))) float f32x16;

__device__ inline unsigned short f2bf(float f) {
    unsigned u = __builtin_bit_cast(unsigned, f);
    return (unsigned short)((u + 0x7fffu + ((u >> 16) & 1u)) >> 16);
}
__device__ inline unsigned pk2(float a, float b) {
    return (unsigned)f2bf(a) | ((unsigned)f2bf(b) << 16);
}
__device__ inline float bf2f(unsigned short u) {
    unsigned x = ((unsigned)u) << 16;
    return __builtin_bit_cast(float, x);
}

__device__ inline void gload16(const void* g, void* l) {
    __builtin_amdgcn_global_load_lds(
        (const __attribute__((address_space(1))) unsigned int*)g,
        (__attribute__((address_space(3))) unsigned int*)(unsigned int)(unsigned long long)l,
        16, 0, 0);
}

// ---------------- merged f32 -> bf16 casts (11 segments; Wo/Wao deferred into gemm8) ----------------
struct CastSegs {
    const float* src[13];
    unsigned short* dst[13];
    int n8[13];
    int ntot8[13];
    int bstart[14];
};

__global__ __launch_bounds__(256)
void castall(CastSegs cs)
{
    int b = blockIdx.x, seg = 0;
    while (seg < 12 && b >= cs.bstart[seg + 1]) seg++;
    int nb = cs.bstart[seg + 1] - cs.bstart[seg];
    int lb = b - cs.bstart[seg];
    const float* in = cs.src[seg];
    unsigned short* out = cs.dst[seg];
    int n8 = cs.n8[seg], ntot = cs.ntot8[seg];
    for (int i = lb * 256 + threadIdx.x; i < ntot; i += nb * 256) {
        int4 o;
        if (i < n8) {
            const float4* p = (const float4*)(in + (size_t)i * 8);
            float4 a = p[0], bb = p[1];
            o.x = pk2(a.x, a.y); o.y = pk2(a.z, a.w);
            o.z = pk2(bb.x, bb.y); o.w = pk2(bb.z, bb.w);
        } else {
            o.x = 0; o.y = 0; o.z = 0; o.w = 0;
        }
        *(int4*)(out + (size_t)i * 8) = o;
    }
}

__global__ __launch_bounds__(256)
void bcat2(const float* __restrict__ q0, const float* __restrict__ k0, const float* __restrict__ v0,
           const float* __restrict__ q1, const float* __restrict__ k1, const float* __restrict__ v1,
           float* __restrict__ d0, float* __restrict__ d1)
{
    int i = blockIdx.x * 256 + threadIdx.x;  // 18432
    int which = i >= 3 * DMODEL;
    int j = which ? i - 3 * DMODEL : i;
    const float* a = which ? q1 : q0;
    const float* b = which ? k1 : k0;
    const float* c = which ? v1 : v0;
    float v = (j < DMODEL) ? a[j] : ((j < 2 * DMODEL) ? b[j - DMODEL] : c[j - 2 * DMODEL]);
    (which ? d1 : d0)[j] = v;
}

// ---------------- GEMM pipelined: 256x128 tile, BK=32, triple-buffer, counted vmcnt ----------------
// Range-routed up to 3 sets (different A/B/C/N/K) + optional cast-role tail blocks.
// Routing puts LONG-POLE blocks (ip: K=4096, single-mb) in t0 [0,e0) so their ~180us runs
// concurrent with the QKV rounds; cast tail (128 blocks) streams Wo/Wao during round 1-2.
// 8 waves as 4M x 2N -> per-wave 64x64 (acc[4][4] = 64 AGPR): 8 ds_read_b128 per 16 MFMA.
// (512,4): 120 regs/wave -> 16 waves/CU (reg quantum at 128, m69) -> 2 blocks/CU.
// (512,6) caps regs at 85 -> acc SPILLS (r11); 2-LDS-buffer buys nothing (r15, reg-capped).
// Per K-tile: 3 gload_lds/thread; vmcnt(3) => prior tile landed; never vmcnt(0) mid-loop.
// LDS slot swizzle = g ^ ((row>>1)&3): 2-way bank aliasing (free), both sides (rule #21).
struct GSet {
    const unsigned short* A;
    const unsigned short* B;
    const float* bias;
    void* C;
    int N, K, nbn;
};

template<int OUTBF>
__global__ __launch_bounds__(512, 4)
void gemm8(GSet s0, GSet s1, GSet s2, int e0, int e1, int e2,
           const float* cs0, unsigned short* cd0,
           const float* cs1, unsigned short* cd1, int cn8)
{
    __shared__ char sm[73728];   // 3 bufs x (A 16K [256x64B] + B 8K [128x64B])
    const int tid = threadIdx.x, lane = tid & 63, wid = tid >> 6;
    const int wm = wid >> 1, wn = wid & 1;       // 4M x 2N wave grid
    const int r15 = lane & 15, g = lane >> 4;

    int nwg = gridDim.x;
    int t0 = (blockIdx.x & 7) * (nwg >> 3) + (blockIdx.x >> 3);

    if (t0 >= e2) {              // cast-role tail blocks (Wo/Wao f32->bf16), 64 blocks each
        int lb = t0 - e2;        // 0..127
        const float* src = (lb >> 6) ? cs1 : cs0;
        unsigned short* dst = (lb >> 6) ? cd1 : cd0;
        int b = lb & 63;
        for (int i = b * 512 + tid; i < cn8; i += 64 * 512) {
            const float4* p = (const float4*)(src + (size_t)i * 8);
            float4 a = p[0], bb = p[1];
            int4 o;
            o.x = pk2(a.x, a.y); o.y = pk2(a.z, a.w);
            o.z = pk2(bb.x, bb.y); o.w = pk2(bb.z, bb.w);
            *(int4*)(dst + (size_t)i * 8) = o;
        }
        return;
    }

    GSet S; int local;
    if (t0 < e0)      { S = s0; local = t0; }
    else if (t0 < e1) { S = s1; local = t0 - e0; }
    else              { S = s2; local = t0 - e1; }
    const int mb = local / S.nbn, nb = local - mb * S.nbn;
    const int m0 = mb * 256, n0 = nb * 128;
    const int K = S.K, N = S.N;
    const unsigned short* A = S.A;
    const unsigned short* B = S.B;
    const float* bias = S.bias;

    // staging: linear LDS dest, inverse-swizzled global source (rule #21); f(row) = (row>>1)&3
    const int fA0 = tid, fA1 = 512 + tid;
    const int rA0 = fA0 >> 2, sA0 = fA0 & 3;
    const int rA1 = fA1 >> 2, sA1 = fA1 & 3;
    const int rB = tid >> 2, sB = tid & 3;
    const unsigned short* Asrc0 = A + (size_t)(m0 + rA0) * K + ((sA0 ^ ((rA0 >> 1) & 3)) << 3);
    const unsigned short* Asrc1 = A + (size_t)(m0 + rA1) * K + ((sA1 ^ ((rA1 >> 1) & 3)) << 3);
    const unsigned short* Bsrc  = B + (size_t)(n0 + rB) * K + ((sB ^ ((rB >> 1) & 3)) << 3);

    f32x4 acc[4][4];
    #pragma unroll
    for (int i = 0; i < 4; i++)
        #pragma unroll
        for (int j = 0; j < 4; j++)
            acc[i][j] = {0.f, 0.f, 0.f, 0.f};

    const int nt = K >> 5;

    auto STAGE = [&](int buf, int kt) {
        char* d = sm + buf * 24576;
        gload16(Asrc0 + (kt << 5), d + fA0 * 16);
        gload16(Asrc1 + (kt << 5), d + fA1 * 16);
        gload16(Bsrc  + (kt << 5), d + 16384 + tid * 16);
    };

    STAGE(0, 0);
    STAGE(1, 1);
    asm volatile("s_waitcnt vmcnt(3)" ::: "memory");   // tile 0 landed (3 newest = tile 1)
    __builtin_amdgcn_s_barrier();

    int cur = 0, nxt = 2;
    for (int t = 0; t < nt; t++) {
        if (t + 2 < nt) STAGE(nxt, t + 2);
        const char* As = sm + cur * 24576;
        const char* Bs = As + 16384;
        short8 bfr[4];
        #pragma unroll
        for (int ni = 0; ni < 4; ni++) {
            int brow = wn * 64 + ni * 16 + r15;
            bfr[ni] = *(const short8*)(Bs + brow * 64 + ((g ^ ((brow >> 1) & 3)) << 4));
        }
        __builtin_amdgcn_s_setprio(1);
        #pragma unroll
        for (int mi = 0; mi < 4; mi++) {
            int arow = wm * 64 + mi * 16 + r15;
            short8 af = *(const short8*)(As + arow * 64 + ((g ^ ((arow >> 1) & 3)) << 4));
            #pragma unroll
            for (int ni = 0; ni < 4; ni++)
                acc[mi][ni] = __builtin_amdgcn_mfma_f32_16x16x32_bf16(af, bfr[ni], acc[mi][ni], 0, 0, 0);
        }
        __builtin_amdgcn_s_setprio(0);
        if (t + 1 < nt) {
            if (t + 2 < nt) { asm volatile("s_waitcnt vmcnt(3)" ::: "memory"); }  // t+1 landed
            else            { asm volatile("s_waitcnt vmcnt(0)" ::: "memory"); }
            __builtin_amdgcn_s_barrier();
        }
        cur = (cur == 2) ? 0 : cur + 1;
        nxt = (nxt == 2) ? 0 : nxt + 1;
    }

    #pragma unroll
    for (int mi = 0; mi < 4; mi++) {
        #pragma unroll
        for (int ni = 0; ni < 4; ni++) {
            int col = n0 + wn * 64 + ni * 16 + r15;
            float bv = bias ? bias[col] : 0.f;
            #pragma unroll
            for (int r = 0; r < 4; r++) {
                int grow = m0 + wm * 64 + mi * 16 + g * 4 + r;
                float v = acc[mi][ni][r] + bv;
                if (OUTBF)
                    ((unsigned short*)S.C)[(size_t)grow * N + col] = f2bf(v);
                else
                    ((float*)S.C)[(size_t)grow * N + col] = v;
            }
        }
    }
}

// ---------------- fused RMS norm + RoPE for Q and K (bf16 in, bf16 out) ----------------
__global__ __launch_bounds__(256)
void rmsropeQK(const unsigned short* __restrict__ qkvb,
               const float* __restrict__ nqw, const float* __restrict__ nkw,
               const float* __restrict__ naqw, const float* __restrict__ nakw,
               const float* __restrict__ cosb, const float* __restrict__ sinb,
               unsigned short* __restrict__ qb, unsigned short* __restrict__ kb,
               unsigned short* __restrict__ ipq)
{
    int wg = blockIdx.x * 4 + (threadIdx.x >> 6);
    int lane = threadIdx.x & 63;
    int s = wg / H, h = wg - s * H;
    const unsigned short* row = qkvb + (size_t)s * (3 * DMODEL);
    unsigned uq = *(const unsigned*)(row + h * HD + lane * 2);
    unsigned uk = *(const unsigned*)(row + DMODEL + h * HD + lane * 2);
    float q0 = bf2f((unsigned short)uq), q1 = bf2f((unsigned short)(uq >> 16));
    float k0 = bf2f((unsigned short)uk), k1 = bf2f((unsigned short)(uk >> 16));
    float sq = q0 * q0 + q1 * q1, sk = k0 * k0 + k1 * k1;
    #pragma unroll
    for (int off = 1; off < 64; off <<= 1) {
        sq += __shfl_xor(sq, off);
        sk += __shfl_xor(sk, off);
    }
    float rq = rsqrtf(sq * (1.f / HD) + 1e-6f) * SM_SCALE;
    float rk = rsqrtf(sk * (1.f / HD) + 1e-6f);
    const float* wq = (s < S_TXT) ? naqw : nqw;
    const float* wk = (s < S_TXT) ? nakw : nkw;
    float xq0 = q0 * rq * wq[lane * 2], xq1 = q1 * rq * wq[lane * 2 + 1];
    float xk0 = k0 * rk * wk[lane * 2], xk1 = k1 * rk * wk[lane * 2 + 1];
    if (s >= S_TXT)
        *(unsigned*)(ipq + (size_t)h * S_IMG * HD + (size_t)(s - S_TXT) * HD + lane * 2) = pk2(xq0, xq1);
    float c0 = cosb[s * HD + lane * 2], c1 = cosb[s * HD + lane * 2 + 1];
    float s0 = sinb[s * HD + lane * 2], s1 = sinb[s * HD + lane * 2 + 1];
    *(unsigned*)(qb + (size_t)h * S_ALL * HD + (size_t)s * HD + lane * 2) =
        pk2(xq0 * c0 - xq1 * s0, xq1 * c1 + xq0 * s1);
    *(unsigned*)(kb + (size_t)h * S_ALL * HD + (size_t)s * HD + lane * 2) =
        pk2(xk0 * c0 - xk1 * s0, xk1 * c1 + xk0 * s1);
}

// ---------------- V transpose: bf16 [S][stride] (col block h*HD) -> [H][HD][Stot] ----------------
__global__ __launch_bounds__(256)
void vtrans(const unsigned short* __restrict__ src, int stride,
            unsigned short* __restrict__ vt, int Stot)
{
    __shared__ unsigned short lv[64 * 130];
    int h = blockIdx.y;
    int s0 = blockIdx.x * 64;
    const unsigned short* base = src + (size_t)s0 * stride + h * HD;
    int tid = threadIdx.x;
    #pragma unroll
    for (int i = 0; i < 4; i++) {
        int slot = tid + 256 * i;
        int row = slot >> 4, c = slot & 15;
        int4 v = *(const int4*)(base + (size_t)row * stride + c * 8);
        unsigned* p = (unsigned*)(lv + row * 130 + c * 8);
        p[0] = (unsigned)v.x; p[1] = (unsigned)v.y; p[2] = (unsigned)v.z; p[3] = (unsigned)v.w;
    }
    __syncthreads();
    #pragma unroll
    for (int i = 0; i < 4; i++) {
        int slot = tid + 256 * i;
        int d = slot >> 3, c8 = slot & 7;
        unsigned w0 = lv[(c8 * 8 + 0) * 130 + d] | ((unsigned)lv[(c8 * 8 + 1) * 130 + d] << 16);
        unsigned w1 = lv[(c8 * 8 + 2) * 130 + d] | ((unsigned)lv[(c8 * 8 + 3) * 130 + d] << 16);
        unsigned w2 = lv[(c8 * 8 + 4) * 130 + d] | ((unsigned)lv[(c8 * 8 + 5) * 130 + d] << 16);
        unsigned w3 = lv[(c8 * 8 + 6) * 130 + d] | ((unsigned)lv[(c8 * 8 + 7) * 130 + d] << 16);
        int4 o = {(int)w0, (int)w1, (int)w2, (int)w3};
        *(int4*)(vt + (size_t)(h * HD + d) * Stot + s0 + c8 * 8) = o;
    }
}

// ---------------- relayout ip K: [N_IP][2*DMODEL] bf16 -> [H][N_IP][HD] bf16 ----------------
__global__ __launch_bounds__(256)
void cast_heads8(const unsigned short* __restrict__ in, unsigned short* __restrict__ out)
{
    int idx = blockIdx.x * 256 + threadIdx.x;   // 24576 = N_IP * DMODEL / 8
    int s = idx / 384;
    int rem = idx - s * 384;
    int h = rem >> 4, d8 = rem & 15;
    int4 v = *(const int4*)(in + (size_t)s * (2 * DMODEL) + h * HD + d8 * 8);
    *(int4*)(out + ((size_t)h * N_IP + s) * HD + d8 * 8) = v;
}

// ---------------- Flash attention v4: 8 warps x 32 q-rows (QBLK=256), KVBLK templated ----------
// 1D grid, XCD-chunked: each XCD owns a contiguous run of heads so the NQB q-blocks
// sharing a head's K/V are L2-co-resident (T1). grid % 8 == 0 guaranteed.
template<int MODE, int KVBLK, int NQB>  // MODE 0 = IP (write bf16 ip_hs), 1 = main (add bf16 ip)
__global__ __launch_bounds__(512, 2)
void flash4(const unsigned short* __restrict__ Q, const unsigned short* __restrict__ Kb,
            const unsigned short* __restrict__ Vt, const unsigned short* __restrict__ ipb,
            unsigned short* __restrict__ Out, int Sq, int Skv)
{
    __shared__ char sm[66560];  // K @0 (<=32K), Vt @32768 (<=32K), scl 1K @65536
    int bid = blockIdx.x;
    int gidx = (bid & 7) * (gridDim.x >> 3) + (bid >> 3);
    const int h = gidx / NQB;
    const int q0 = (gidx - h * NQB) * 256;
    const int tid = threadIdx.x, w = tid >> 6, lane = tid & 63;
    const int l31 = lane & 31, hi = lane >> 5;
    const int T2 = KVBLK / 32, K4 = KVBLK / 16, SLOTV = KVBLK / 8, NL = KVBLK / 32;
    const int VROWB = KVBLK * 2;

    const unsigned short* Qh = Q + ((size_t)h * Sq + q0 + w * 32 + l31) * HD + hi * 8;
    short8 qf[8];
    #pragma unroll
    for (int c = 0; c < 8; c++)
        qf[c] = *(const short8*)(Qh + c * 16);

    float m = -3.0e38f, lsum = 0.f;
    f32x16 o[4];
    #pragma unroll
    for (int dn = 0; dn < 4; dn++)
        #pragma unroll
        for (int r = 0; r < 16; r++) o[dn][r] = 0.f;

    const unsigned short* Kh = Kb + (size_t)h * Skv * HD;
    const unsigned short* Vth = Vt + (size_t)h * HD * Skv;
    float* scl = (float*)(sm + 65536) + w * 32;
    const int nt = Skv / KVBLK;

    for (int t = 0; t < nt; t++) {
        int kv0 = t * KVBLK;
        #pragma unroll
        for (int cc = 0; cc < NL; cc++) {
            int f = cc * 512 + tid;
            int row = f >> 4, slot = f & 15;
            gload16(Kh + (size_t)(kv0 + row) * HD + (((slot * 16) ^ ((row & 7) << 4)) >> 1),
                    sm + f * 16);
        }
        #pragma unroll
        for (int cc = 0; cc < NL; cc++) {
            int f = cc * 512 + tid;
            int d = f / SLOTV, slot = f % SLOTV;
            gload16(Vth + (size_t)d * Skv + kv0 + (((slot * 16) ^ ((d & 7) << 4)) >> 1),
                    sm + 32768 + f * 16);
        }
        __syncthreads();

        f32x16 st[T2];
        __builtin_amdgcn_s_setprio(1);
        #pragma unroll
        for (int t2 = 0; t2 < T2; t2++) {
            #pragma unroll
            for (int r = 0; r < 16; r++) st[t2][r] = 0.f;
            #pragma unroll
            for (int c = 0; c < 8; c++) {
                int krow = t2 * 32 + l31;
                short8 kf = *(const short8*)(sm + krow * 256 + ((c * 32 + hi * 16) ^ ((krow & 7) << 4)));
                st[t2] = __builtin_amdgcn_mfma_f32_32x32x16_bf16(kf, qf[c], st[t2], 0, 0, 0);
            }
        }
        __builtin_amdgcn_s_setprio(0);

        float pmax = st[0][0];
        #pragma unroll
        for (int t2 = 0; t2 < T2; t2++)
            #pragma unroll
            for (int r = 0; r < 16; r++) pmax = fmaxf(pmax, st[t2][r]);
        pmax = fmaxf(pmax, __shfl_xor(pmax, 32));

        if (!__all(pmax - m <= 8.0f)) {     // defer-max (T13)
            float mn = fmaxf(m, pmax);
            float sc = __expf(m - mn);
            m = mn;
            lsum *= sc;
            if (hi == 0) scl[l31] = sc;
            float scb[16];
            #pragma unroll
            for (int r = 0; r < 16; r++)
                scb[r] = scl[(r & 3) + 8 * (r >> 2) + 4 * hi];
            #pragma unroll
            for (int dn = 0; dn < 4; dn++)
                #pragma unroll
                for (int r = 0; r < 16; r++) o[dn][r] *= scb[r];
        }

        float psum = 0.f;
        #pragma unroll
        for (int t2 = 0; t2 < T2; t2++)
            #pragma unroll
            for (int r = 0; r < 16; r++) {
                float p = __expf(st[t2][r] - m);
                st[t2][r] = p;
                psum += p;
            }
        psum += __shfl_xor(psum, 32);
        lsum += psum;

        short8 pa[K4];
        #pragma unroll
        for (int k4 = 0; k4 < K4; k4++) {
            unsigned U  = pk2(st[(k4 * 8 + 0) >> 4][(k4 * 8 + 0) & 15], st[(k4 * 8 + 1) >> 4][(k4 * 8 + 1) & 15]);
            unsigned V  = pk2(st[(k4 * 8 + 2) >> 4][(k4 * 8 + 2) & 15], st[(k4 * 8 + 3) >> 4][(k4 * 8 + 3) & 15]);
            unsigned U2 = pk2(st[(k4 * 8 + 4) >> 4][(k4 * 8 + 4) & 15], st[(k4 * 8 + 5) >> 4][(k4 * 8 + 5) & 15]);
            unsigned V2 = pk2(st[(k4 * 8 + 6) >> 4][(k4 * 8 + 6) & 15], st[(k4 * 8 + 7) >> 4][(k4 * 8 + 7) & 15]);
            unsigned SU = __shfl_xor(U, 32), SU2 = __shfl_xor(U2, 32);
            unsigned SV = __shfl_xor(V, 32), SV2 = __shfl_xor(V2, 32);
            uint4 wv;
            wv.x = hi ? SU2 : U;
            wv.y = hi ? SV2 : V;
            wv.z = hi ? U2 : SU;
            wv.w = hi ? V2 : SV;
            pa[k4] = __builtin_bit_cast(short8, wv);
        }

        __builtin_amdgcn_s_setprio(1);
        #pragma unroll
        for (int dn = 0; dn < 4; dn++) {
            #pragma unroll
            for (int k4 = 0; k4 < K4; k4++) {
                int vrow = dn * 32 + l31;
                short8 vf = *(const short8*)(sm + 32768 + vrow * VROWB + ((k4 * 32 + hi * 16) ^ ((vrow & 7) << 4)));
                o[dn] = __builtin_amdgcn_mfma_f32_32x32x16_bf16(pa[k4], vf, o[dn], 0, 0, 0);
            }
        }
        __builtin_amdgcn_s_setprio(0);
        __syncthreads();
    }

    if (hi == 0) scl[l31] = 1.f / lsum;
    float linv[16];
    #pragma unroll
    for (int r = 0; r < 16; r++)
        linv[r] = scl[(r & 3) + 8 * (r >> 2) + 4 * hi];
    #pragma unroll
    for (int dn = 0; dn < 4; dn++) {
        #pragma unroll
        for (int r = 0; r < 16; r++) {
            int qrow = q0 + w * 32 + (r & 3) + 8 * (r >> 2) + 4 * hi;
            int col = h * HD + dn * 32 + l31;
            float val = o[dn][r] * linv[r];
            if (MODE == 1 && qrow >= S_TXT)
                val += bf2f(ipb[(size_t)(qrow - S_TXT) * DMODEL + col]);
            Out[(size_t)qrow * DMODEL + col] = f2bf(val);
        }
    }
}

// ---------------- launch ----------------
extern "C" void kernel_launch(void* const* d_in, const int* in_sizes, int n_in,
                              void* d_out, int out_size, void* d_ws, size_t ws_size,
                              hipStream_t stream)
{
    const float* hs   = (const float*)d_in[0];
    const float* enc  = (const float*)d_in[1];
    const float* iemb = (const float*)d_in[2];
    const float* cosb = (const float*)d_in[3];
    const float* sinb = (const float*)d_in[4];
    const float* Wq  = (const float*)d_in[5];  const float* bq  = (const float*)d_in[6];
    const float* Wk  = (const float*)d_in[7];  const float* bk  = (const float*)d_in[8];
    const float* Wv  = (const float*)d_in[9];  const float* bv  = (const float*)d_in[10];
    const float* Waq = (const float*)d_in[11]; const float* baq = (const float*)d_in[12];
    const float* Wak = (const float*)d_in[13]; const float* bak = (const float*)d_in[14];
    const float* Wav = (const float*)d_in[15]; const float* bav = (const float*)d_in[16];
    const float* Wo  = (const float*)d_in[17]; const float* bo  = (const float*)d_in[18];
    const float* Wao = (const float*)d_in[19]; const float* bao = (const float*)d_in[20];
    const float* nq  = (const float*)d_in[21]; const float* nk  = (const float*)d_in[22];
    const float* naq = (const float*)d_in[23]; const float* nak = (const float*)d_in[24];
    const float* Wkip = (const float*)d_in[25]; const float* Wvip = (const float*)d_in[26];
    (void)in_sizes; (void)n_in; (void)out_size; (void)ws_size;

    char* ws = (char*)d_ws;
    size_t off = 0;
    auto alloc = [&](size_t b) { char* p = ws + off; off += (b + 255) & ~(size_t)255; return p; };
    unsigned short* qkvb    = (unsigned short*)alloc((size_t)S_ALL * 3 * DMODEL * 2);  // txt rows 0..511, img 512..2559
    unsigned short* ipkvb   = (unsigned short*)alloc((size_t)256 * 2 * DMODEL * 2);    // rows 64..255 pad
    unsigned short* hs_bf   = (unsigned short*)alloc((size_t)S_IMG * DMODEL * 2);
    unsigned short* enc_bf  = (unsigned short*)alloc((size_t)S_TXT * DMODEL * 2);
    unsigned short* iemb_bf = (unsigned short*)alloc((size_t)256 * EMB * 2);           // rows 64..255 pad (zeros)
    unsigned short* Wqkv  = (unsigned short*)alloc((size_t)3 * DMODEL * DMODEL * 2);
    unsigned short* Waqkv = (unsigned short*)alloc((size_t)3 * DMODEL * DMODEL * 2);
    unsigned short* Wo_b  = (unsigned short*)alloc((size_t)DMODEL * DMODEL * 2);
    unsigned short* Wao_b = (unsigned short*)alloc((size_t)DMODEL * DMODEL * 2);
    unsigned short* Wip   = (unsigned short*)alloc((size_t)2 * DMODEL * EMB * 2);
    float* bqkv  = (float*)alloc(3 * DMODEL * 4);
    float* baqkv = (float*)alloc(3 * DMODEL * 4);
    unsigned short* qb    = (unsigned short*)alloc((size_t)H * S_ALL * HD * 2);
    unsigned short* kbf   = (unsigned short*)alloc((size_t)H * S_ALL * HD * 2);
    unsigned short* vtb   = (unsigned short*)alloc((size_t)H * HD * S_ALL * 2);
    unsigned short* ipqb  = (unsigned short*)alloc((size_t)H * S_IMG * HD * 2);
    unsigned short* ipkb  = (unsigned short*)alloc((size_t)H * N_IP * HD * 2);
    unsigned short* ipvtb = (unsigned short*)alloc((size_t)H * HD * N_IP * 2);
    unsigned short* ipbuf = (unsigned short*)alloc((size_t)S_IMG * DMODEL * 2);
    unsigned short* attnb = (unsigned short*)alloc((size_t)S_ALL * DMODEL * 2);

    const size_t DD = (size_t)DMODEL * DMODEL;
    const size_t DE = (size_t)DMODEL * EMB;
    const int D8 = (int)(DD / 8), E8 = (int)(DE / 8);

    // merged cast dispatch: activations + QKV weights + ip weights (Wo/Wao deferred into gemm8)
    CastSegs cs;
    const float* srcs[11] = {hs, enc, iemb, Wq, Wk, Wv, Waq, Wak, Wav, Wkip, Wvip};
    unsigned short* dsts[11] = {hs_bf, enc_bf, iemb_bf,
                                Wqkv, Wqkv + DD, Wqkv + 2 * DD,
                                Waqkv, Waqkv + DD, Waqkv + 2 * DD,
                                Wip, Wip + DE};
    int n8s[11]  = {S_IMG * DMODEL / 8, S_TXT * DMODEL / 8, N_IP * EMB / 8,
                    D8, D8, D8, D8, D8, D8, E8, E8};
    int nt8s[11] = {S_IMG * DMODEL / 8, S_TXT * DMODEL / 8, 256 * EMB / 8,
                    D8, D8, D8, D8, D8, D8, E8, E8};
    int acc = 0;
    for (int i = 0; i < 11; i++) {
        cs.src[i] = srcs[i]; cs.dst[i] = dsts[i];
        cs.n8[i] = n8s[i]; cs.ntot8[i] = nt8s[i];
        cs.bstart[i] = acc;
        int nb = (nt8s[i] + 8191) / 8192;
        acc += (nb < 1 ? 1 : nb);
    }
    for (int i = 11; i < 14; i++) cs.bstart[i] = acc;

    dim3 blk(256);
    castall<<<dim3(acc), blk, 0, stream>>>(cs);
    bcat2<<<dim3(72), blk, 0, stream>>>(bq, bk, bv, baq, bak, bav, bqkv, baqkv);

    // mega QKV dispatch, long-pole-first routing:
    //   ip [0,48) | img QKV [48,624) | txt QKV [624,768) | Wo/Wao cast [768,896)
    GSet sIp  = {iemb_bf, Wip,  nullptr, ipkvb,                           2 * DMODEL, EMB,    48};
    GSet sImg = {hs_bf,  Wqkv,  bqkv,  qkvb + (size_t)S_TXT * 3 * DMODEL, 3 * DMODEL, DMODEL, 72};
    GSet sTxt = {enc_bf, Waqkv, baqkv, qkvb,                              3 * DMODEL, DMODEL, 72};
    gemm8<1><<<dim3(896), dim3(512), 0, stream>>>(
        sIp, sImg, sTxt, 48, 624, 768,
        Wo, Wo_b, Wao, Wao_b, D8);

    rmsropeQK<<<dim3(15360), blk, 0, stream>>>(qkvb, nq, nk, naq, nak, cosb, sinb, qb, kbf, ipqb);
    vtrans<<<dim3(40, 24), blk, 0, stream>>>(qkvb + 2 * DMODEL, 3 * DMODEL, vtb, S_ALL);
    cast_heads8<<<dim3(96), blk, 0, stream>>>(ipkvb, ipkb);
    vtrans<<<dim3(1, 24), blk, 0, stream>>>(ipkvb + DMODEL, 2 * DMODEL, ipvtb, N_IP);

    dim3 fblk(512);
    flash4<0, 64, 8><<<dim3(192), fblk, 0, stream>>>(ipqb, ipkb, ipvtb, nullptr, ipbuf, S_IMG, N_IP);
    flash4<1, 128, 10><<<dim3(240), fblk, 0, stream>>>(qb, kbf, vtb, ipbuf, attnb, S_ALL, S_ALL);

    // out-proj dispatch: img [0,192) -> Wo, txt [192,240) -> Wao; no ip set, no cast tail
    GSet oImg = {attnb + (size_t)S_TXT * DMODEL, Wo_b,  bo,  d_out,                                DMODEL, DMODEL, 24};
    GSet oTxt = {attnb,                          Wao_b, bao, (float*)d_out + (size_t)S_IMG * DMODEL, DMODEL, DMODEL, 24};
    gemm8<0><<<dim3(240), dim3(512), 0, stream>>>(
        oImg, oTxt, oTxt, 192, 240, 240,
        nullptr, nullptr, nullptr, nullptr, 0);
}

// Round 17
// 553.670 us; speedup vs baseline: 1.0376x; 1.0103x over previous
//
#include <hip/hip_runtime.h>
#include <hip/hip_bf16.h>

#define H 24
#define HD 128
#define DMODEL 3072
#define S_IMG 2048
#define S_TXT 512
#define S_ALL 2560
#define EMB 4096
#define N_IP 64
#define SM_SCALE 0.08838834764831845f  // 1/sqrt(128)

typedef __attribute__((ext_vector_type(8))) short short8;
typedef __attribute__((ext_vector_type(4))) float f32x4;
typedef __attribute__((ext_vector_type(16))) float f32x16;

__device__ inline unsigned short f2bf(float f) {
    unsigned u = __builtin_bit_cast(unsigned, f);
    return (unsigned short)((u + 0x7fffu + ((u >> 16) & 1u)) >> 16);
}
__device__ inline unsigned pk2(float a, float b) {
    return (unsigned)f2bf(a) | ((unsigned)f2bf(b) << 16);
}
__device__ inline float bf2f(unsigned short u) {
    unsigned x = ((unsigned)u) << 16;
    return __builtin_bit_cast(float, x);
}

__device__ inline void gload16(const void* g, void* l) {
    __builtin_amdgcn_global_load_lds(
        (const __attribute__((address_space(1))) unsigned int*)g,
        (__attribute__((address_space(3))) unsigned int*)(unsigned int)(unsigned long long)l,
        16, 0, 0);
}

// ---------------- merged f32 -> bf16 casts (11 segments; Wo/Wao deferred into gemm8) ----------------
struct CastSegs {
    const float* src[13];
    unsigned short* dst[13];
    int n8[13];
    int ntot8[13];
    int bstart[14];
};

__global__ __launch_bounds__(256)
void castall(CastSegs cs)
{
    int b = blockIdx.x, seg = 0;
    while (seg < 12 && b >= cs.bstart[seg + 1]) seg++;
    int nb = cs.bstart[seg + 1] - cs.bstart[seg];
    int lb = b - cs.bstart[seg];
    const float* in = cs.src[seg];
    unsigned short* out = cs.dst[seg];
    int n8 = cs.n8[seg], ntot = cs.ntot8[seg];
    for (int i = lb * 256 + threadIdx.x; i < ntot; i += nb * 256) {
        int4 o;
        if (i < n8) {
            const float4* p = (const float4*)(in + (size_t)i * 8);
            float4 a = p[0], bb = p[1];
            o.x = pk2(a.x, a.y); o.y = pk2(a.z, a.w);
            o.z = pk2(bb.x, bb.y); o.w = pk2(bb.z, bb.w);
        } else {
            o.x = 0; o.y = 0; o.z = 0; o.w = 0;
        }
        *(int4*)(out + (size_t)i * 8) = o;
    }
}

__global__ __launch_bounds__(256)
void bcat2(const float* __restrict__ q0, const float* __restrict__ k0, const float* __restrict__ v0,
           const float* __restrict__ q1, const float* __restrict__ k1, const float* __restrict__ v1,
           float* __restrict__ d0, float* __restrict__ d1)
{
    int i = blockIdx.x * 256 + threadIdx.x;  // 18432
    int which = i >= 3 * DMODEL;
    int j = which ? i - 3 * DMODEL : i;
    const float* a = which ? q1 : q0;
    const float* b = which ? k1 : k0;
    const float* c = which ? v1 : v0;
    float v = (j < DMODEL) ? a[j] : ((j < 2 * DMODEL) ? b[j - DMODEL] : c[j - 2 * DMODEL]);
    (which ? d1 : d0)[j] = v;
}

// ---------------- GEMM pipelined: 256x128 tile, BK=32, triple-buffer, counted vmcnt ----------------
// Range-routed up to 3 sets (different A/B/C/N/K) + optional cast-role tail blocks.
// Routing puts LONG-POLE blocks (ip: K=4096, single-mb) in t0 [0,e0) so their ~180us runs
// concurrent with the QKV rounds; cast tail (128 blocks) streams Wo/Wao during round 1-2.
// 8 waves as 4M x 2N -> per-wave 64x64 (acc[4][4] = 64 AGPR): 8 ds_read_b128 per 16 MFMA.
// (512,4): 120 regs/wave -> 16 waves/CU (reg quantum at 128, m69) -> 2 blocks/CU.
// (512,6) caps regs at 85 -> acc SPILLS (r11); 2-LDS-buffer buys nothing (r15, reg-capped).
// Per K-tile: 3 gload_lds/thread; vmcnt(3) => prior tile landed; never vmcnt(0) mid-loop.
// LDS slot swizzle = g ^ ((row>>1)&3): 2-way bank aliasing (free), both sides (rule #21).
struct GSet {
    const unsigned short* A;
    const unsigned short* B;
    const float* bias;
    void* C;
    int N, K, nbn;
};

template<int OUTBF>
__global__ __launch_bounds__(512, 4)
void gemm8(GSet s0, GSet s1, GSet s2, int e0, int e1, int e2,
           const float* cs0, unsigned short* cd0,
           const float* cs1, unsigned short* cd1, int cn8)
{
    __shared__ char sm[73728];   // 3 bufs x (A 16K [256x64B] + B 8K [128x64B])
    const int tid = threadIdx.x, lane = tid & 63, wid = tid >> 6;
    const int wm = wid >> 1, wn = wid & 1;       // 4M x 2N wave grid
    const int r15 = lane & 15, g = lane >> 4;

    int nwg = gridDim.x;
    int t0 = (blockIdx.x & 7) * (nwg >> 3) + (blockIdx.x >> 3);

    if (t0 >= e2) {              // cast-role tail blocks (Wo/Wao f32->bf16), 64 blocks each
        int lb = t0 - e2;        // 0..127
        const float* src = (lb >> 6) ? cs1 : cs0;
        unsigned short* dst = (lb >> 6) ? cd1 : cd0;
        int b = lb & 63;
        for (int i = b * 512 + tid; i < cn8; i += 64 * 512) {
            const float4* p = (const float4*)(src + (size_t)i * 8);
            float4 a = p[0], bb = p[1];
            int4 o;
            o.x = pk2(a.x, a.y); o.y = pk2(a.z, a.w);
            o.z = pk2(bb.x, bb.y); o.w = pk2(bb.z, bb.w);
            *(int4*)(dst + (size_t)i * 8) = o;
        }
        return;
    }

    GSet S; int local;
    if (t0 < e0)      { S = s0; local = t0; }
    else if (t0 < e1) { S = s1; local = t0 - e0; }
    else              { S = s2; local = t0 - e1; }
    const int mb = local / S.nbn, nb = local - mb * S.nbn;
    const int m0 = mb * 256, n0 = nb * 128;
    const int K = S.K, N = S.N;
    const unsigned short* A = S.A;
    const unsigned short* B = S.B;
    const float* bias = S.bias;

    // staging: linear LDS dest, inverse-swizzled global source (rule #21); f(row) = (row>>1)&3
    const int fA0 = tid, fA1 = 512 + tid;
    const int rA0 = fA0 >> 2, sA0 = fA0 & 3;
    const int rA1 = fA1 >> 2, sA1 = fA1 & 3;
    const int rB = tid >> 2, sB = tid & 3;
    const unsigned short* Asrc0 = A + (size_t)(m0 + rA0) * K + ((sA0 ^ ((rA0 >> 1) & 3)) << 3);
    const unsigned short* Asrc1 = A + (size_t)(m0 + rA1) * K + ((sA1 ^ ((rA1 >> 1) & 3)) << 3);
    const unsigned short* Bsrc  = B + (size_t)(n0 + rB) * K + ((sB ^ ((rB >> 1) & 3)) << 3);

    f32x4 acc[4][4];
    #pragma unroll
    for (int i = 0; i < 4; i++)
        #pragma unroll
        for (int j = 0; j < 4; j++)
            acc[i][j] = {0.f, 0.f, 0.f, 0.f};

    const int nt = K >> 5;

    auto STAGE = [&](int buf, int kt) {
        char* d = sm + buf * 24576;
        gload16(Asrc0 + (kt << 5), d + fA0 * 16);
        gload16(Asrc1 + (kt << 5), d + fA1 * 16);
        gload16(Bsrc  + (kt << 5), d + 16384 + tid * 16);
    };

    STAGE(0, 0);
    STAGE(1, 1);
    asm volatile("s_waitcnt vmcnt(3)" ::: "memory");   // tile 0 landed (3 newest = tile 1)
    __builtin_amdgcn_s_barrier();

    int cur = 0, nxt = 2;
    for (int t = 0; t < nt; t++) {
        if (t + 2 < nt) STAGE(nxt, t + 2);
        const char* As = sm + cur * 24576;
        const char* Bs = As + 16384;
        short8 bfr[4];
        #pragma unroll
        for (int ni = 0; ni < 4; ni++) {
            int brow = wn * 64 + ni * 16 + r15;
            bfr[ni] = *(const short8*)(Bs + brow * 64 + ((g ^ ((brow >> 1) & 3)) << 4));
        }
        __builtin_amdgcn_s_setprio(1);
        #pragma unroll
        for (int mi = 0; mi < 4; mi++) {
            int arow = wm * 64 + mi * 16 + r15;
            short8 af = *(const short8*)(As + arow * 64 + ((g ^ ((arow >> 1) & 3)) << 4));
            #pragma unroll
            for (int ni = 0; ni < 4; ni++)
                acc[mi][ni] = __builtin_amdgcn_mfma_f32_16x16x32_bf16(af, bfr[ni], acc[mi][ni], 0, 0, 0);
        }
        __builtin_amdgcn_s_setprio(0);
        if (t + 1 < nt) {
            if (t + 2 < nt) { asm volatile("s_waitcnt vmcnt(3)" ::: "memory"); }  // t+1 landed
            else            { asm volatile("s_waitcnt vmcnt(0)" ::: "memory"); }
            __builtin_amdgcn_s_barrier();
        }
        cur = (cur == 2) ? 0 : cur + 1;
        nxt = (nxt == 2) ? 0 : nxt + 1;
    }

    #pragma unroll
    for (int mi = 0; mi < 4; mi++) {
        #pragma unroll
        for (int ni = 0; ni < 4; ni++) {
            int col = n0 + wn * 64 + ni * 16 + r15;
            float bv = bias ? bias[col] : 0.f;
            #pragma unroll
            for (int r = 0; r < 4; r++) {
                int grow = m0 + wm * 64 + mi * 16 + g * 4 + r;
                float v = acc[mi][ni][r] + bv;
                if (OUTBF)
                    ((unsigned short*)S.C)[(size_t)grow * N + col] = f2bf(v);
                else
                    ((float*)S.C)[(size_t)grow * N + col] = v;
            }
        }
    }
}

// ---------------- merged epilogue: rmsropeQK + vtrans(main) + cast_heads8 + vtrans(ip) ----------------
// All four read qkvb/ipkvb (ready after the mega GEMM) and write disjoint buffers -> one
// block-range-routed dispatch removes 3 launch gaps + ragged tails. 256 threads each.
__device__ inline void vtrans_body(const unsigned short* __restrict__ base, int stride,
                                   unsigned short* __restrict__ vt, int Stot,
                                   int s0, int h, unsigned short* lv, int tid)
{
    const unsigned short* src = base + (size_t)s0 * stride + h * HD;
    #pragma unroll
    for (int i = 0; i < 4; i++) {
        int slot = tid + 256 * i;
        int row = slot >> 4, c = slot & 15;
        int4 v = *(const int4*)(src + (size_t)row * stride + c * 8);
        unsigned* p = (unsigned*)(lv + row * 130 + c * 8);
        p[0] = (unsigned)v.x; p[1] = (unsigned)v.y; p[2] = (unsigned)v.z; p[3] = (unsigned)v.w;
    }
    __syncthreads();
    #pragma unroll
    for (int i = 0; i < 4; i++) {
        int slot = tid + 256 * i;
        int d = slot >> 3, c8 = slot & 7;
        unsigned w0 = lv[(c8 * 8 + 0) * 130 + d] | ((unsigned)lv[(c8 * 8 + 1) * 130 + d] << 16);
        unsigned w1 = lv[(c8 * 8 + 2) * 130 + d] | ((unsigned)lv[(c8 * 8 + 3) * 130 + d] << 16);
        unsigned w2 = lv[(c8 * 8 + 4) * 130 + d] | ((unsigned)lv[(c8 * 8 + 5) * 130 + d] << 16);
        unsigned w3 = lv[(c8 * 8 + 6) * 130 + d] | ((unsigned)lv[(c8 * 8 + 7) * 130 + d] << 16);
        int4 o = {(int)w0, (int)w1, (int)w2, (int)w3};
        *(int4*)(vt + (size_t)(h * HD + d) * Stot + s0 + c8 * 8) = o;
    }
}

__global__ __launch_bounds__(256)
void epilogue(const unsigned short* __restrict__ qkvb, const unsigned short* __restrict__ ipkvb,
              const float* __restrict__ nqw, const float* __restrict__ nkw,
              const float* __restrict__ naqw, const float* __restrict__ nakw,
              const float* __restrict__ cosb, const float* __restrict__ sinb,
              unsigned short* __restrict__ qb, unsigned short* __restrict__ kb,
              unsigned short* __restrict__ ipq,
              unsigned short* __restrict__ vtb, unsigned short* __restrict__ ipkb,
              unsigned short* __restrict__ ipvtb)
{
    __shared__ unsigned short lv[64 * 130];
    const int b = blockIdx.x;
    const int tid = threadIdx.x;

    if (b < 15360) {                       // ---- rmsropeQK (15360 blocks x 4 waves) ----
        int wg = b * 4 + (tid >> 6);
        int lane = tid & 63;
        int s = wg / H, h = wg - s * H;
        const unsigned short* row = qkvb + (size_t)s * (3 * DMODEL);
        unsigned uq = *(const unsigned*)(row + h * HD + lane * 2);
        unsigned uk = *(const unsigned*)(row + DMODEL + h * HD + lane * 2);
        float q0 = bf2f((unsigned short)uq), q1 = bf2f((unsigned short)(uq >> 16));
        float k0 = bf2f((unsigned short)uk), k1 = bf2f((unsigned short)(uk >> 16));
        float sq = q0 * q0 + q1 * q1, sk = k0 * k0 + k1 * k1;
        #pragma unroll
        for (int off = 1; off < 64; off <<= 1) {
            sq += __shfl_xor(sq, off);
            sk += __shfl_xor(sk, off);
        }
        float rq = rsqrtf(sq * (1.f / HD) + 1e-6f) * SM_SCALE;
        float rk = rsqrtf(sk * (1.f / HD) + 1e-6f);
        const float* wq = (s < S_TXT) ? naqw : nqw;
        const float* wk = (s < S_TXT) ? nakw : nkw;
        float xq0 = q0 * rq * wq[lane * 2], xq1 = q1 * rq * wq[lane * 2 + 1];
        float xk0 = k0 * rk * wk[lane * 2], xk1 = k1 * rk * wk[lane * 2 + 1];
        if (s >= S_TXT)
            *(unsigned*)(ipq + (size_t)h * S_IMG * HD + (size_t)(s - S_TXT) * HD + lane * 2) = pk2(xq0, xq1);
        float c0 = cosb[s * HD + lane * 2], c1 = cosb[s * HD + lane * 2 + 1];
        float s0 = sinb[s * HD + lane * 2], s1 = sinb[s * HD + lane * 2 + 1];
        *(unsigned*)(qb + (size_t)h * S_ALL * HD + (size_t)s * HD + lane * 2) =
            pk2(xq0 * c0 - xq1 * s0, xq1 * c1 + xq0 * s1);
        *(unsigned*)(kb + (size_t)h * S_ALL * HD + (size_t)s * HD + lane * 2) =
            pk2(xk0 * c0 - xk1 * s0, xk1 * c1 + xk0 * s1);
    } else if (b < 16320) {                // ---- vtrans main (960 blocks) ----
        int local = b - 15360;
        int bx = local % 40, h = local / 40;
        vtrans_body(qkvb + 2 * DMODEL, 3 * DMODEL, vtb, S_ALL, bx * 64, h, lv, tid);
    } else if (b < 16416) {                // ---- cast_heads8 (96 blocks) ----
        int idx = (b - 16320) * 256 + tid; // over N_IP*DMODEL/8
        int s = idx / 384;
        int rem = idx - s * 384;
        int h = rem >> 4, d8 = rem & 15;
        int4 v = *(const int4*)(ipkvb + (size_t)s * (2 * DMODEL) + h * HD + d8 * 8);
        *(int4*)(ipkb + ((size_t)h * N_IP + s) * HD + d8 * 8) = v;
    } else {                               // ---- vtrans ip (24 blocks) ----
        int h = b - 16416;
        vtrans_body(ipkvb + DMODEL, 2 * DMODEL, ipvtb, N_IP, 0, h, lv, tid);
    }
}

// ---------------- Flash attention v4: 8 warps x 32 q-rows (QBLK=256), KVBLK templated ----------
// 1D grid, XCD-chunked: each XCD owns a contiguous run of heads so the NQB q-blocks
// sharing a head's K/V are L2-co-resident (T1). grid % 8 == 0 guaranteed.
template<int MODE, int KVBLK, int NQB>  // MODE 0 = IP (write bf16 ip_hs), 1 = main (add bf16 ip)
__global__ __launch_bounds__(512, 2)
void flash4(const unsigned short* __restrict__ Q, const unsigned short* __restrict__ Kb,
            const unsigned short* __restrict__ Vt, const unsigned short* __restrict__ ipb,
            unsigned short* __restrict__ Out, int Sq, int Skv)
{
    __shared__ char sm[66560];  // K @0 (<=32K), Vt @32768 (<=32K), scl 1K @65536
    int bid = blockIdx.x;
    int gidx = (bid & 7) * (gridDim.x >> 3) + (bid >> 3);
    const int h = gidx / NQB;
    const int q0 = (gidx - h * NQB) * 256;
    const int tid = threadIdx.x, w = tid >> 6, lane = tid & 63;
    const int l31 = lane & 31, hi = lane >> 5;
    const int T2 = KVBLK / 32, K4 = KVBLK / 16, SLOTV = KVBLK / 8, NL = KVBLK / 32;
    const int VROWB = KVBLK * 2;

    const unsigned short* Qh = Q + ((size_t)h * Sq + q0 + w * 32 + l31) * HD + hi * 8;
    short8 qf[8];
    #pragma unroll
    for (int c = 0; c < 8; c++)
        qf[c] = *(const short8*)(Qh + c * 16);

    float m = -3.0e38f, lsum = 0.f;
    f32x16 o[4];
    #pragma unroll
    for (int dn = 0; dn < 4; dn++)
        #pragma unroll
        for (int r = 0; r < 16; r++) o[dn][r] = 0.f;

    const unsigned short* Kh = Kb + (size_t)h * Skv * HD;
    const unsigned short* Vth = Vt + (size_t)h * HD * Skv;
    float* scl = (float*)(sm + 65536) + w * 32;
    const int nt = Skv / KVBLK;

    for (int t = 0; t < nt; t++) {
        int kv0 = t * KVBLK;
        #pragma unroll
        for (int cc = 0; cc < NL; cc++) {
            int f = cc * 512 + tid;
            int row = f >> 4, slot = f & 15;
            gload16(Kh + (size_t)(kv0 + row) * HD + (((slot * 16) ^ ((row & 7) << 4)) >> 1),
                    sm + f * 16);
        }
        #pragma unroll
        for (int cc = 0; cc < NL; cc++) {
            int f = cc * 512 + tid;
            int d = f / SLOTV, slot = f % SLOTV;
            gload16(Vth + (size_t)d * Skv + kv0 + (((slot * 16) ^ ((d & 7) << 4)) >> 1),
                    sm + 32768 + f * 16);
        }
        __syncthreads();

        f32x16 st[T2];
        __builtin_amdgcn_s_setprio(1);
        #pragma unroll
        for (int t2 = 0; t2 < T2; t2++) {
            #pragma unroll
            for (int r = 0; r < 16; r++) st[t2][r] = 0.f;
            #pragma unroll
            for (int c = 0; c < 8; c++) {
                int krow = t2 * 32 + l31;
                short8 kf = *(const short8*)(sm + krow * 256 + ((c * 32 + hi * 16) ^ ((krow & 7) << 4)));
                st[t2] = __builtin_amdgcn_mfma_f32_32x32x16_bf16(kf, qf[c], st[t2], 0, 0, 0);
            }
        }
        __builtin_amdgcn_s_setprio(0);

        float pmax = st[0][0];
        #pragma unroll
        for (int t2 = 0; t2 < T2; t2++)
            #pragma unroll
            for (int r = 0; r < 16; r++) pmax = fmaxf(pmax, st[t2][r]);
        pmax = fmaxf(pmax, __shfl_xor(pmax, 32));

        if (!__all(pmax - m <= 8.0f)) {     // defer-max (T13)
            float mn = fmaxf(m, pmax);
            float sc = __expf(m - mn);
            m = mn;
            lsum *= sc;
            if (hi == 0) scl[l31] = sc;
            float scb[16];
            #pragma unroll
            for (int r = 0; r < 16; r++)
                scb[r] = scl[(r & 3) + 8 * (r >> 2) + 4 * hi];
            #pragma unroll
            for (int dn = 0; dn < 4; dn++)
                #pragma unroll
                for (int r = 0; r < 16; r++) o[dn][r] *= scb[r];
        }

        float psum = 0.f;
        #pragma unroll
        for (int t2 = 0; t2 < T2; t2++)
            #pragma unroll
            for (int r = 0; r < 16; r++) {
                float p = __expf(st[t2][r] - m);
                st[t2][r] = p;
                psum += p;
            }
        psum += __shfl_xor(psum, 32);
        lsum += psum;

        short8 pa[K4];
        #pragma unroll
        for (int k4 = 0; k4 < K4; k4++) {
            unsigned U  = pk2(st[(k4 * 8 + 0) >> 4][(k4 * 8 + 0) & 15], st[(k4 * 8 + 1) >> 4][(k4 * 8 + 1) & 15]);
            unsigned V  = pk2(st[(k4 * 8 + 2) >> 4][(k4 * 8 + 2) & 15], st[(k4 * 8 + 3) >> 4][(k4 * 8 + 3) & 15]);
            unsigned U2 = pk2(st[(k4 * 8 + 4) >> 4][(k4 * 8 + 4) & 15], st[(k4 * 8 + 5) >> 4][(k4 * 8 + 5) & 15]);
            unsigned V2 = pk2(st[(k4 * 8 + 6) >> 4][(k4 * 8 + 6) & 15], st[(k4 * 8 + 7) >> 4][(k4 * 8 + 7) & 15]);
            unsigned SU = __shfl_xor(U, 32), SU2 = __shfl_xor(U2, 32);
            unsigned SV = __shfl_xor(V, 32), SV2 = __shfl_xor(V2, 32);
            uint4 wv;
            wv.x = hi ? SU2 : U;
            wv.y = hi ? SV2 : V;
            wv.z = hi ? U2 : SU;
            wv.w = hi ? V2 : SV;
            pa[k4] = __builtin_bit_cast(short8, wv);
        }

        __builtin_amdgcn_s_setprio(1);
        #pragma unroll
        for (int dn = 0; dn < 4; dn++) {
            #pragma unroll
            for (int k4 = 0; k4 < K4; k4++) {
                int vrow = dn * 32 + l31;
                short8 vf = *(const short8*)(sm + 32768 + vrow * VROWB + ((k4 * 32 + hi * 16) ^ ((vrow & 7) << 4)));
                o[dn] = __builtin_amdgcn_mfma_f32_32x32x16_bf16(pa[k4], vf, o[dn], 0, 0, 0);
            }
        }
        __builtin_amdgcn_s_setprio(0);
        __syncthreads();
    }

    if (hi == 0) scl[l31] = 1.f / lsum;
    float linv[16];
    #pragma unroll
    for (int r = 0; r < 16; r++)
        linv[r] = scl[(r & 3) + 8 * (r >> 2) + 4 * hi];
    #pragma unroll
    for (int dn = 0; dn < 4; dn++) {
        #pragma unroll
        for (int r = 0; r < 16; r++) {
            int qrow = q0 + w * 32 + (r & 3) + 8 * (r >> 2) + 4 * hi;
            int col = h * HD + dn * 32 + l31;
            float val = o[dn][r] * linv[r];
            if (MODE == 1 && qrow >= S_TXT)
                val += bf2f(ipb[(size_t)(qrow - S_TXT) * DMODEL + col]);
            Out[(size_t)qrow * DMODEL + col] = f2bf(val);
        }
    }
}

// ---------------- launch ----------------
extern "C" void kernel_launch(void* const* d_in, const int* in_sizes, int n_in,
                              void* d_out, int out_size, void* d_ws, size_t ws_size,
                              hipStream_t stream)
{
    const float* hs   = (const float*)d_in[0];
    const float* enc  = (const float*)d_in[1];
    const float* iemb = (const float*)d_in[2];
    const float* cosb = (const float*)d_in[3];
    const float* sinb = (const float*)d_in[4];
    const float* Wq  = (const float*)d_in[5];  const float* bq  = (const float*)d_in[6];
    const float* Wk  = (const float*)d_in[7];  const float* bk  = (const float*)d_in[8];
    const float* Wv  = (const float*)d_in[9];  const float* bv  = (const float*)d_in[10];
    const float* Waq = (const float*)d_in[11]; const float* baq = (const float*)d_in[12];
    const float* Wak = (const float*)d_in[13]; const float* bak = (const float*)d_in[14];
    const float* Wav = (const float*)d_in[15]; const float* bav = (const float*)d_in[16];
    const float* Wo  = (const float*)d_in[17]; const float* bo  = (const float*)d_in[18];
    const float* Wao = (const float*)d_in[19]; const float* bao = (const float*)d_in[20];
    const float* nq  = (const float*)d_in[21]; const float* nk  = (const float*)d_in[22];
    const float* naq = (const float*)d_in[23]; const float* nak = (const float*)d_in[24];
    const float* Wkip = (const float*)d_in[25]; const float* Wvip = (const float*)d_in[26];
    (void)in_sizes; (void)n_in; (void)out_size; (void)ws_size;

    char* ws = (char*)d_ws;
    size_t off = 0;
    auto alloc = [&](size_t b) { char* p = ws + off; off += (b + 255) & ~(size_t)255; return p; };
    unsigned short* qkvb    = (unsigned short*)alloc((size_t)S_ALL * 3 * DMODEL * 2);  // txt rows 0..511, img 512..2559
    unsigned short* ipkvb   = (unsigned short*)alloc((size_t)256 * 2 * DMODEL * 2);    // rows 64..255 pad
    unsigned short* hs_bf   = (unsigned short*)alloc((size_t)S_IMG * DMODEL * 2);
    unsigned short* enc_bf  = (unsigned short*)alloc((size_t)S_TXT * DMODEL * 2);
    unsigned short* iemb_bf = (unsigned short*)alloc((size_t)256 * EMB * 2);           // rows 64..255 pad (zeros)
    unsigned short* Wqkv  = (unsigned short*)alloc((size_t)3 * DMODEL * DMODEL * 2);
    unsigned short* Waqkv = (unsigned short*)alloc((size_t)3 * DMODEL * DMODEL * 2);
    unsigned short* Wo_b  = (unsigned short*)alloc((size_t)DMODEL * DMODEL * 2);
    unsigned short* Wao_b = (unsigned short*)alloc((size_t)DMODEL * DMODEL * 2);
    unsigned short* Wip   = (unsigned short*)alloc((size_t)2 * DMODEL * EMB * 2);
    float* bqkv  = (float*)alloc(3 * DMODEL * 4);
    float* baqkv = (float*)alloc(3 * DMODEL * 4);
    unsigned short* qb    = (unsigned short*)alloc((size_t)H * S_ALL * HD * 2);
    unsigned short* kbf   = (unsigned short*)alloc((size_t)H * S_ALL * HD * 2);
    unsigned short* vtb   = (unsigned short*)alloc((size_t)H * HD * S_ALL * 2);
    unsigned short* ipqb  = (unsigned short*)alloc((size_t)H * S_IMG * HD * 2);
    unsigned short* ipkb  = (unsigned short*)alloc((size_t)H * N_IP * HD * 2);
    unsigned short* ipvtb = (unsigned short*)alloc((size_t)H * HD * N_IP * 2);
    unsigned short* ipbuf = (unsigned short*)alloc((size_t)S_IMG * DMODEL * 2);
    unsigned short* attnb = (unsigned short*)alloc((size_t)S_ALL * DMODEL * 2);

    const size_t DD = (size_t)DMODEL * DMODEL;
    const size_t DE = (size_t)DMODEL * EMB;
    const int D8 = (int)(DD / 8), E8 = (int)(DE / 8);

    // merged cast dispatch: activations + QKV weights + ip weights (Wo/Wao deferred into gemm8)
    CastSegs cs;
    const float* srcs[11] = {hs, enc, iemb, Wq, Wk, Wv, Waq, Wak, Wav, Wkip, Wvip};
    unsigned short* dsts[11] = {hs_bf, enc_bf, iemb_bf,
                                Wqkv, Wqkv + DD, Wqkv + 2 * DD,
                                Waqkv, Waqkv + DD, Waqkv + 2 * DD,
                                Wip, Wip + DE};
    int n8s[11]  = {S_IMG * DMODEL / 8, S_TXT * DMODEL / 8, N_IP * EMB / 8,
                    D8, D8, D8, D8, D8, D8, E8, E8};
    int nt8s[11] = {S_IMG * DMODEL / 8, S_TXT * DMODEL / 8, 256 * EMB / 8,
                    D8, D8, D8, D8, D8, D8, E8, E8};
    int acc = 0;
    for (int i = 0; i < 11; i++) {
        cs.src[i] = srcs[i]; cs.dst[i] = dsts[i];
        cs.n8[i] = n8s[i]; cs.ntot8[i] = nt8s[i];
        cs.bstart[i] = acc;
        int nb = (nt8s[i] + 8191) / 8192;
        acc += (nb < 1 ? 1 : nb);
    }
    for (int i = 11; i < 14; i++) cs.bstart[i] = acc;

    dim3 blk(256);
    castall<<<dim3(acc), blk, 0, stream>>>(cs);
    bcat2<<<dim3(72), blk, 0, stream>>>(bq, bk, bv, baq, bak, bav, bqkv, baqkv);

    // mega QKV dispatch, long-pole-first routing:
    //   ip [0,48) | img QKV [48,624) | txt QKV [624,768) | Wo/Wao cast [768,896)
    GSet sIp  = {iemb_bf, Wip,  nullptr, ipkvb,                           2 * DMODEL, EMB,    48};
    GSet sImg = {hs_bf,  Wqkv,  bqkv,  qkvb + (size_t)S_TXT * 3 * DMODEL, 3 * DMODEL, DMODEL, 72};
    GSet sTxt = {enc_bf, Waqkv, baqkv, qkvb,                              3 * DMODEL, DMODEL, 72};
    gemm8<1><<<dim3(896), dim3(512), 0, stream>>>(
        sIp, sImg, sTxt, 48, 624, 768,
        Wo, Wo_b, Wao, Wao_b, D8);

    // merged epilogue: rmsropeQK [0,15360) | vtrans-main [15360,16320) |
    //                  cast_heads8 [16320,16416) | vtrans-ip [16416,16440)
    epilogue<<<dim3(16440), blk, 0, stream>>>(
        qkvb, ipkvb, nq, nk, naq, nak, cosb, sinb,
        qb, kbf, ipqb, vtb, ipkb, ipvtb);

    dim3 fblk(512);
    flash4<0, 64, 8><<<dim3(192), fblk, 0, stream>>>(ipqb, ipkb, ipvtb, nullptr, ipbuf, S_IMG, N_IP);
    flash4<1, 128, 10><<<dim3(240), fblk, 0, stream>>>(qb, kbf, vtb, ipbuf, attnb, S_ALL, S_ALL);

    // out-proj dispatch: img [0,192) -> Wo, txt [192,240) -> Wao; no ip set, no cast tail
    GSet oImg = {attnb + (size_t)S_TXT * DMODEL, Wo_b,  bo,  d_out,                                DMODEL, DMODEL, 24};
    GSet oTxt = {attnb,                          Wao_b, bao, (float*)d_out + (size_t)S_IMG * DMODEL, DMODEL, DMODEL, 24};
    gemm8<0><<<dim3(240), dim3(512), 0, stream>>>(
        oImg, oTxt, oTxt, 192, 240, 240,
        nullptr, nullptr, nullptr, nullptr, 0);
}